// Round 1
// baseline (799.703 us; speedup 1.0000x reference)
//
#include <hip/hip_runtime.h>

#define NCN 50000   // nodes per type (N_C == N_N)
#define NE  500000  // edges per type
#define DF  128     // feature dim
#define SCAN_NB 49  // ceil(50000/1024)

// ---------------------------------------------------------------------------
// CSR build: histogram of 3 dst arrays (+2 src arrays for GraphConv out-deg)
// ---------------------------------------------------------------------------
__global__ __launch_bounds__(256) void hist5_k(
    const int* __restrict__ cc_src, const int* __restrict__ cc_dst,
    const int* __restrict__ cn_src, const int* __restrict__ cn_dst,
    const int* __restrict__ nn_dst,
    int* __restrict__ deg3, int* __restrict__ cnt2)
{
    int i = blockIdx.x * 256 + threadIdx.x;
    if (i >= NE) return;
    atomicAdd(&deg3[0 * NCN + cc_dst[i]], 1);
    atomicAdd(&deg3[1 * NCN + cn_dst[i]], 1);
    atomicAdd(&deg3[2 * NCN + nn_dst[i]], 1);
    atomicAdd(&cnt2[0 * NCN + cc_src[i]], 1);
    atomicAdd(&cnt2[1 * NCN + cn_src[i]], 1);
}

// Pass 1: per-block (1024 elems) partial sums. grid = (SCAN_NB, 3)
__global__ __launch_bounds__(256) void scan_partial_k(
    const int* __restrict__ deg3, int* __restrict__ part3, int n)
{
    const int ty = blockIdx.y;
    const int* d = deg3 + (size_t)ty * n;
    const int tid = threadIdx.x;
    const int base = blockIdx.x * 1024 + tid * 4;
    int s = 0;
    #pragma unroll
    for (int j = 0; j < 4; ++j) { int idx = base + j; if (idx < n) s += d[idx]; }
    __shared__ int red[256];
    red[tid] = s;
    __syncthreads();
    #pragma unroll
    for (int off = 128; off > 0; off >>= 1) {
        if (tid < off) red[tid] += red[tid + off];
        __syncthreads();
    }
    if (tid == 0) part3[ty * 64 + blockIdx.x] = red[0];
}

// Pass 2: exclusive scan of the SCAN_NB partials per type. grid = 3
__global__ __launch_bounds__(64) void scan_mid_k(int* __restrict__ part3, int nb)
{
    if (threadIdx.x == 0) {
        int* p = part3 + blockIdx.x * 64;
        int run = 0;
        for (int i = 0; i < nb; ++i) { int v = p[i]; p[i] = run; run += v; }
    }
}

// Pass 3: final exclusive scan -> rowptr + cursor copy. grid = (SCAN_NB, 3)
__global__ __launch_bounds__(256) void scan_final_k(
    const int* __restrict__ deg3, const int* __restrict__ part3,
    int* __restrict__ rp3, int* __restrict__ cur3, int n)
{
    const int ty = blockIdx.y;
    const int* d = deg3 + (size_t)ty * n;
    int* rp  = rp3  + (size_t)ty * (n + 1);
    int* cur = cur3 + (size_t)ty * n;
    const int tid = threadIdx.x;
    const int base = blockIdx.x * 1024 + tid * 4;
    int v[4]; int s = 0;
    #pragma unroll
    for (int j = 0; j < 4; ++j) { int idx = base + j; v[j] = (idx < n) ? d[idx] : 0; s += v[j]; }
    __shared__ int sc[256];
    sc[tid] = s;
    __syncthreads();
    #pragma unroll
    for (int off = 1; off < 256; off <<= 1) {
        int t = (tid >= off) ? sc[tid - off] : 0;
        __syncthreads();
        sc[tid] += t;
        __syncthreads();
    }
    int run = sc[tid] - s + part3[ty * 64 + blockIdx.x];  // exclusive prefix
    #pragma unroll
    for (int j = 0; j < 4; ++j) {
        int idx = base + j;
        if (idx < n) {
            rp[idx] = run; cur[idx] = run; run += v[j];
            if (idx == n - 1) rp[n] = run;
        }
    }
}

__global__ __launch_bounds__(256) void fill3_k(
    const int* __restrict__ cc_src, const int* __restrict__ cc_dst,
    const int* __restrict__ cn_src, const int* __restrict__ cn_dst,
    const int* __restrict__ nn_src, const int* __restrict__ nn_dst,
    int* __restrict__ cur3, int* __restrict__ col3)
{
    int i = blockIdx.x * 256 + threadIdx.x;
    if (i >= NE) return;
    { int p = atomicAdd(&cur3[0 * NCN + cc_dst[i]], 1); col3[0 * NE + p] = cc_src[i]; }
    { int p = atomicAdd(&cur3[1 * NCN + cn_dst[i]], 1); col3[1 * NE + p] = cn_src[i]; }
    { int p = atomicAdd(&cur3[2 * NCN + nn_dst[i]], 1); col3[2 * NE + p] = nn_src[i]; }
}

// norm_src = max(out_deg,1)^-0.5 for cc_src and cn_src tables
__global__ __launch_bounds__(256) void srcnorm_k(
    const int* __restrict__ cnt2, float* __restrict__ snorm2, int n2)
{
    int i = blockIdx.x * 256 + threadIdx.x;
    if (i >= n2) return;
    int c = cnt2[i]; if (c < 1) c = 1;
    snorm2[i] = rsqrtf((float)c);
}

// ---------------------------------------------------------------------------
// Pull aggregation: one wave (64 lanes) per destination row, 2 floats/lane.
// MODE 0: GraphConv (dst scale = rsqrt(max(deg,1)))   MODE 1: SAGE mean (1/deg)
// ---------------------------------------------------------------------------
template<int MODE>
__global__ __launch_bounds__(256) void agg_pull_k(
    const float* __restrict__ X, const int* __restrict__ rowptr,
    const int* __restrict__ colidx, const float* __restrict__ srcscale,
    float* __restrict__ out, int n)
{
    int gid = blockIdx.x * 256 + threadIdx.x;
    int row = gid >> 6;
    int lane = threadIdx.x & 63;
    if (row >= n) return;
    int e0 = rowptr[row], e1 = rowptr[row + 1];
    float ax = 0.f, ay = 0.f;
    for (int e = e0; e < e1; ++e) {
        int s = colidx[e];
        float sc = (srcscale != nullptr) ? srcscale[s] : 1.0f;
        const float2 v = *(const float2*)(X + (size_t)s * DF + lane * 2);
        ax = fmaf(v.x, sc, ax);
        ay = fmaf(v.y, sc, ay);
    }
    int deg = e1 - e0; if (deg < 1) deg = 1;
    float dsc = (MODE == 0) ? rsqrtf((float)deg) : (1.0f / (float)deg);
    float2 o; o.x = ax * dsc; o.y = ay * dsc;
    *(float2*)(out + (size_t)row * DF + lane * 2) = o;
}

// ---------------------------------------------------------------------------
// fp32 GEMM: Y[M,128] = sum_s A_s[M,128] @ W_s[128,128] + b0 + b1, opt ReLU.
// Block tile: 64 rows x 128 cols, 256 threads, thread = 8 rows x 4 cols.
// LDS: W chunk [64][128] (32KB) + padded A tile [64][68] (17KB) -> 3 blk/CU.
// In-place (Y aliasing an A_s) is safe: all global A reads are barriered
// before any thread reaches the store epilogue, and rows are block-private.
// ---------------------------------------------------------------------------
template<int NSRC, bool RELU>
__global__ __launch_bounds__(256, 3) void gemm_k(
    const float* __restrict__ A0, const float* __restrict__ A1, const float* __restrict__ A2,
    const float* __restrict__ W0, const float* __restrict__ W1, const float* __restrict__ W2,
    const float* __restrict__ b0, const float* __restrict__ b1,
    float* __restrict__ Y, int M)
{
    __shared__ float Ws[64 * 128];
    __shared__ float As[64 * 68];
    const int tid = threadIdx.x;
    const int r0 = blockIdx.x * 64;
    const int tr = tid >> 5;   // 0..7  -> rows tr*8..tr*8+7
    const int tc = tid & 31;   // 0..31 -> cols tc*4..tc*4+3

    float4 acc[8];
    #pragma unroll
    for (int i = 0; i < 8; ++i) acc[i] = make_float4(0.f, 0.f, 0.f, 0.f);

    const float* Aarr[3] = {A0, A1, A2};
    const float* Warr[3] = {W0, W1, W2};

    const int lr = tid >> 2;   // 0..63 (row within tile for loads)
    const int seg = tid & 3;   // 0..3
    int gr = r0 + lr; if (gr > M - 1) gr = M - 1;   // clamped load row

    #pragma unroll
    for (int s = 0; s < NSRC; ++s) {
        const float* A = Aarr[s];
        const float* W = Warr[s];
        for (int kc = 0; kc < 128; kc += 64) {
            __syncthreads();   // protect LDS reads of previous chunk
            // stage W rows kc..kc+63 (flat 2048 float4, coalesced)
            const float4* Wg = (const float4*)(W + kc * 128);
            float4* Ws4 = (float4*)Ws;
            #pragma unroll
            for (int i = 0; i < 8; ++i) Ws4[tid + i * 256] = Wg[tid + i * 256];
            // stage A rows r0..r0+63, cols kc..kc+63 (4 lanes/row, 64B groups)
            const float* Ar = A + (size_t)gr * DF + kc;
            #pragma unroll
            for (int i = 0; i < 4; ++i) {
                float4 v = *(const float4*)(Ar + (i * 4 + seg) * 4);
                *(float4*)(As + lr * 68 + (i * 4 + seg) * 4) = v;
            }
            __syncthreads();
            #pragma unroll 4
            for (int k = 0; k < 64; ++k) {
                float4 w = *(const float4*)(Ws + k * 128 + tc * 4);
                #pragma unroll
                for (int i = 0; i < 8; ++i) {
                    float a = As[(tr * 8 + i) * 68 + k];
                    acc[i].x = fmaf(a, w.x, acc[i].x);
                    acc[i].y = fmaf(a, w.y, acc[i].y);
                    acc[i].z = fmaf(a, w.z, acc[i].z);
                    acc[i].w = fmaf(a, w.w, acc[i].w);
                }
            }
        }
    }

    float4 bias = make_float4(0.f, 0.f, 0.f, 0.f);
    if (b0) { bias.x  = b0[tc * 4]; bias.y  = b0[tc * 4 + 1]; bias.z  = b0[tc * 4 + 2]; bias.w  = b0[tc * 4 + 3]; }
    if (b1) { bias.x += b1[tc * 4]; bias.y += b1[tc * 4 + 1]; bias.z += b1[tc * 4 + 2]; bias.w += b1[tc * 4 + 3]; }

    #pragma unroll
    for (int i = 0; i < 8; ++i) {
        int r = r0 + tr * 8 + i;
        if (r < M) {
            float4 v;
            v.x = acc[i].x + bias.x; v.y = acc[i].y + bias.y;
            v.z = acc[i].z + bias.z; v.w = acc[i].w + bias.w;
            if (RELU) {
                v.x = fmaxf(v.x, 0.f); v.y = fmaxf(v.y, 0.f);
                v.z = fmaxf(v.z, 0.f); v.w = fmaxf(v.w, 0.f);
            }
            *(float4*)(Y + (size_t)r * DF + tc * 4) = v;
        }
    }
}

// ---------------------------------------------------------------------------
extern "C" void kernel_launch(void* const* d_in, const int* in_sizes, int n_in,
                              void* d_out, int out_size, void* d_ws, size_t ws_size,
                              hipStream_t stream)
{
    (void)in_sizes; (void)n_in; (void)out_size; (void)ws_size;
    const float* feat_C   = (const float*)d_in[0];
    const float* feat_N   = (const float*)d_in[1];
    const float* W1_cc    = (const float*)d_in[2];
    const float* b1_cc    = (const float*)d_in[3];
    const float* W1_cn    = (const float*)d_in[4];
    const float* b1_cn    = (const float*)d_in[5];
    const float* W1_self  = (const float*)d_in[6];
    const float* W1_neigh = (const float*)d_in[7];
    const float* b1_nn    = (const float*)d_in[8];
    const float* W2_cc    = (const float*)d_in[9];
    const float* b2_cc    = (const float*)d_in[10];
    const float* W2_cn    = (const float*)d_in[11];
    const float* b2_cn    = (const float*)d_in[12];
    const float* W2_self  = (const float*)d_in[13];
    const float* W2_neigh = (const float*)d_in[14];
    const float* b2_nn    = (const float*)d_in[15];
    const int* cc_src = (const int*)d_in[16];
    const int* cc_dst = (const int*)d_in[17];
    const int* cn_src = (const int*)d_in[18];
    const int* cn_dst = (const int*)d_in[19];
    const int* nn_src = (const int*)d_in[20];
    const int* nn_dst = (const int*)d_in[21];

    char* ws = (char*)d_ws;
    size_t off = 0;
    auto take = [&](size_t bytes) -> char* {
        char* p = ws + off;
        off = (off + bytes + 255) & ~(size_t)255;
        return p;
    };
    int* cnts   = (int*)take((size_t)5 * NCN * sizeof(int));  // deg3 (3N) + cnt2 (2N)
    int* deg3   = cnts;
    int* cnt2   = cnts + 3 * NCN;
    int* rp3    = (int*)take((size_t)3 * (NCN + 1) * sizeof(int));
    int* cur3   = (int*)take((size_t)3 * NCN * sizeof(int));
    int* part3  = (int*)take((size_t)3 * 64 * sizeof(int));
    int* col3   = (int*)take((size_t)3 * NE * sizeof(int));
    float* snorm2 = (float*)take((size_t)2 * NCN * sizeof(float));
    float* aggA = (float*)take((size_t)NCN * DF * sizeof(float));
    float* aggB = (float*)take((size_t)NCN * DF * sizeof(float));

    float* oC = (float*)d_out;           // also hosts hC (layer-1)
    float* oN = oC + (size_t)NCN * DF;   // also hosts hN (layer-1)

    const int edgeBlocks = (NE + 255) / 256;
    const int aggBlocks  = (NCN * 64 + 255) / 256;   // one wave per row
    const int gemmBlocks = (NCN + 63) / 64;

    // ---- CSR + norms (recomputed every call; deterministic inputs) ----
    hipMemsetAsync(cnts, 0, (size_t)5 * NCN * sizeof(int), stream);
    hist5_k<<<edgeBlocks, 256, 0, stream>>>(cc_src, cc_dst, cn_src, cn_dst, nn_dst, deg3, cnt2);
    scan_partial_k<<<dim3(SCAN_NB, 3), 256, 0, stream>>>(deg3, part3, NCN);
    scan_mid_k<<<3, 64, 0, stream>>>(part3, SCAN_NB);
    scan_final_k<<<dim3(SCAN_NB, 3), 256, 0, stream>>>(deg3, part3, rp3, cur3, NCN);
    fill3_k<<<edgeBlocks, 256, 0, stream>>>(cc_src, cc_dst, cn_src, cn_dst, nn_src, nn_dst, cur3, col3);
    srcnorm_k<<<(2 * NCN + 255) / 256, 256, 0, stream>>>(cnt2, snorm2, 2 * NCN);

    // ---- layer 1 ----
    // hC = relu( agg_cc(feat_C) @ W1_cc + b1_cc )
    agg_pull_k<0><<<aggBlocks, 256, 0, stream>>>(feat_C, rp3 + 0 * (NCN + 1), col3 + 0 * NE,
                                                 snorm2 + 0 * NCN, aggA, NCN);
    gemm_k<1, true><<<gemmBlocks, 256, 0, stream>>>(aggA, nullptr, nullptr,
                                                    W1_cc, nullptr, nullptr,
                                                    b1_cc, nullptr, oC, NCN);
    // hN = relu( agg_cn(feat_C)@W1_cn + agg_nn(feat_N)@W1_neigh + feat_N@W1_self + b1_cn + b1_nn )
    agg_pull_k<0><<<aggBlocks, 256, 0, stream>>>(feat_C, rp3 + 1 * (NCN + 1), col3 + 1 * NE,
                                                 snorm2 + 1 * NCN, aggA, NCN);
    agg_pull_k<1><<<aggBlocks, 256, 0, stream>>>(feat_N, rp3 + 2 * (NCN + 1), col3 + 2 * NE,
                                                 nullptr, aggB, NCN);
    gemm_k<3, true><<<gemmBlocks, 256, 0, stream>>>(aggA, aggB, feat_N,
                                                    W1_cn, W1_neigh, W1_self,
                                                    b1_cn, b1_nn, oN, NCN);

    // ---- layer 2 ----
    // must read hC (= oC) in both aggs BEFORE overwriting oC
    agg_pull_k<0><<<aggBlocks, 256, 0, stream>>>(oC, rp3 + 0 * (NCN + 1), col3 + 0 * NE,
                                                 snorm2 + 0 * NCN, aggA, NCN);
    agg_pull_k<0><<<aggBlocks, 256, 0, stream>>>(oC, rp3 + 1 * (NCN + 1), col3 + 1 * NE,
                                                 snorm2 + 1 * NCN, aggB, NCN);
    gemm_k<1, false><<<gemmBlocks, 256, 0, stream>>>(aggA, nullptr, nullptr,
                                                     W2_cc, nullptr, nullptr,
                                                     b2_cc, nullptr, oC, NCN);
    agg_pull_k<1><<<aggBlocks, 256, 0, stream>>>(oN, rp3 + 2 * (NCN + 1), col3 + 2 * NE,
                                                 nullptr, aggA, NCN);
    // in-place: reads hN (= oN) as A2, writes oN (row-parallel, barriered loads)
    gemm_k<3, false><<<gemmBlocks, 256, 0, stream>>>(aggB, aggA, oN,
                                                     W2_cn, W2_neigh, W2_self,
                                                     b2_cn, b2_nn, oN, NCN);
}

// Round 2
// 523.485 us; speedup vs baseline: 1.5277x; 1.5277x over previous
//
#include <hip/hip_runtime.h>

#define NCN 50000   // nodes per type (N_C == N_N)
#define NE  500000  // edges per type
#define DF  128     // feature dim

// Binning parameters
#define BSHIFT 9                 // 512 dst nodes per bucket
#define NBUCK 98                 // ceil(50000/512)
#define BK 128                   // padded bucket count
#define CAP 7168                 // records per bucket (expected ~5120, uniform)
#define CHUNK 4096               // edges per binA block

// ---------------------------------------------------------------------------
// Phase A: block-local counting sort of CHUNK edges into NBUCK dst-buckets,
// flushed as contiguous runs (one global atomic per block x bucket).
// streams: 0=cc(dst,src) 1=cn(dst,src) 2=nn(dst,src) 3=cc_src 4=cn_src(count only)
// ---------------------------------------------------------------------------
__global__ __launch_bounds__(256) void binA_k(
    const int* __restrict__ cc_src, const int* __restrict__ cc_dst,
    const int* __restrict__ cn_src, const int* __restrict__ cn_dst,
    const int* __restrict__ nn_src, const int* __restrict__ nn_dst,
    uint2* __restrict__ R, int* __restrict__ bc)
{
    const int s = blockIdx.y;
    const int* key; const int* pay;
    switch (s) {
      case 0: key = cc_dst; pay = cc_src; break;
      case 1: key = cn_dst; pay = cn_src; break;
      case 2: key = nn_dst; pay = nn_src; break;
      case 3: key = cc_src; pay = nullptr; break;
      default: key = cn_src; pay = nullptr; break;
    }
    __shared__ uint2 rec[CHUNK];
    __shared__ int lhist[BK], lofs[BK], lcur[BK], gbase[BK];
    __shared__ int ls[256];
    const int tid = threadIdx.x;
    const int base = blockIdx.x * CHUNK;

    int k[16], p[16];
    #pragma unroll
    for (int j = 0; j < 16; ++j) {
        int e = base + j * 256 + tid;
        bool valid = (e < NE);
        k[j] = valid ? key[e] : -1;
        p[j] = (valid && pay) ? pay[e] : 0;
    }
    if (tid < BK) lhist[tid] = 0;
    __syncthreads();
    #pragma unroll
    for (int j = 0; j < 16; ++j)
        if (k[j] >= 0) atomicAdd(&lhist[k[j] >> BSHIFT], 1);
    __syncthreads();
    // inclusive scan of 128 bucket counts (Hillis-Steele in LDS)
    int v = (tid < BK) ? lhist[tid] : 0;
    ls[tid] = v;
    __syncthreads();
    #pragma unroll
    for (int off = 1; off < 128; off <<= 1) {
        int t = (tid >= off) ? ls[tid - off] : 0;
        __syncthreads();
        ls[tid] += t;
        __syncthreads();
    }
    if (tid < BK) { int e = ls[tid] - v; lofs[tid] = e; lcur[tid] = e; }
    __syncthreads();
    // place records bucket-partitioned in LDS
    #pragma unroll
    for (int j = 0; j < 16; ++j) {
        if (k[j] >= 0) {
            int b = k[j] >> BSHIFT;
            int pos = atomicAdd(&lcur[b], 1);
            rec[pos] = make_uint2((unsigned)k[j], (unsigned)p[j]);
        }
    }
    __syncthreads();
    // reserve contiguous global runs
    if (tid < BK) {
        int c = lcur[tid] - lofs[tid];
        gbase[tid] = (c > 0) ? atomicAdd(&bc[s * BK + tid], c) : 0;
    }
    __syncthreads();
    int total = ls[127];
    for (int i = tid; i < total; i += 256) {
        uint2 r = rec[i];
        int b = (int)(r.x >> BSHIFT);
        int gi = gbase[b] + (i - lofs[b]);
        R[((size_t)s * NBUCK + b) * CAP + gi] = r;
    }
}

// ---------------------------------------------------------------------------
// Phase B: one block per (bucket, stream).
//  dst streams (0-2): LDS histogram + scan -> rowptr (dense), fill col segment
//                     (contiguous ~20KB region, single block -> dense writeback)
//  src streams (3-4): histogram -> snorm = rsqrt(max(cnt,1)) (dense)
// ---------------------------------------------------------------------------
__global__ __launch_bounds__(256) void binB_k(
    const uint2* __restrict__ R, const int* __restrict__ bc,
    int* __restrict__ rp3, int* __restrict__ col3, float* __restrict__ snorm2)
{
    const int b = blockIdx.x;    // 0..NBUCK-1
    const int s = blockIdx.y;    // 0..4
    const int tid = threadIdx.x;
    __shared__ int cnt[512];
    __shared__ int lofs[512];
    __shared__ int ls[256];
    __shared__ int sbase;

    const int nrec = bc[s * BK + b];
    const uint2* rec = R + ((size_t)s * NBUCK + b) * CAP;

    for (int i = tid; i < 512; i += 256) cnt[i] = 0;
    __syncthreads();
    for (int i = tid; i < nrec; i += 256)
        atomicAdd(&cnt[rec[i].x & 511], 1);
    __syncthreads();

    if (s >= 3) {   // count-only streams -> src norms
        float* sn = snorm2 + (size_t)(s - 3) * NCN;
        for (int j = tid; j < 512; j += 256) {
            int d = b * 512 + j;
            if (d < NCN) { int c = cnt[j]; if (c < 1) c = 1; sn[d] = rsqrtf((float)c); }
        }
        return;
    }

    // bucket's global col base = sum of bc[s][0..b)
    {
        int v = (tid < b) ? bc[s * BK + tid] : 0;
        ls[tid] = v;
        __syncthreads();
        for (int off = 128; off > 0; off >>= 1) {
            if (tid < off) ls[tid] += ls[tid + off];
            __syncthreads();
        }
        if (tid == 0) sbase = ls[0];
        __syncthreads();
    }
    const int colBase = sbase;

    // exclusive scan of 512 counts (pairs per thread)
    int v0 = cnt[2 * tid], v1 = cnt[2 * tid + 1];
    int pairSum = v0 + v1;
    ls[tid] = pairSum;
    __syncthreads();
    #pragma unroll
    for (int off = 1; off < 256; off <<= 1) {
        int t = (tid >= off) ? ls[tid - off] : 0;
        __syncthreads();
        ls[tid] += t;
        __syncthreads();
    }
    int excl = ls[tid] - pairSum;
    lofs[2 * tid] = excl;
    lofs[2 * tid + 1] = excl + v0;
    __syncthreads();
    const int total = ls[255];

    // rowptr (dense write)
    int* rp = rp3 + (size_t)s * (NCN + 1);
    for (int j = tid; j < 512; j += 256) {
        int d = b * 512 + j;
        if (d < NCN) rp[d] = colBase + lofs[j];
    }
    if (b == NBUCK - 1 && tid == 0) rp[NCN] = colBase + total;
    __syncthreads();   // rp/lofs reads done before cursor mutation

    // fill col segment (lofs doubles as cursors)
    int* col = col3 + (size_t)s * NE + colBase;
    for (int i = tid; i < nrec; i += 256) {
        uint2 r = rec[i];
        int pos = atomicAdd(&lofs[r.x & 511], 1);
        col[pos] = (int)r.y;
    }
}

// ---------------------------------------------------------------------------
// Pull aggregation: one wave (64 lanes) per destination row, 2 floats/lane.
// MODE 0: GraphConv (dst scale = rsqrt(max(deg,1)))   MODE 1: SAGE mean (1/deg)
// ---------------------------------------------------------------------------
template<int MODE>
__global__ __launch_bounds__(256) void agg_pull_k(
    const float* __restrict__ X, const int* __restrict__ rowptr,
    const int* __restrict__ colidx, const float* __restrict__ srcscale,
    float* __restrict__ out, int n)
{
    int gid = blockIdx.x * 256 + threadIdx.x;
    int row = gid >> 6;
    int lane = threadIdx.x & 63;
    if (row >= n) return;
    int e0 = rowptr[row], e1 = rowptr[row + 1];
    float ax = 0.f, ay = 0.f;
    int e = e0;
    for (; e + 2 <= e1; e += 2) {
        int s0 = colidx[e], s1 = colidx[e + 1];
        float c0 = (srcscale != nullptr) ? srcscale[s0] : 1.0f;
        float c1 = (srcscale != nullptr) ? srcscale[s1] : 1.0f;
        const float2 u0 = *(const float2*)(X + (size_t)s0 * DF + lane * 2);
        const float2 u1 = *(const float2*)(X + (size_t)s1 * DF + lane * 2);
        ax = fmaf(u0.x, c0, ax); ay = fmaf(u0.y, c0, ay);
        ax = fmaf(u1.x, c1, ax); ay = fmaf(u1.y, c1, ay);
    }
    if (e < e1) {
        int s0 = colidx[e];
        float c0 = (srcscale != nullptr) ? srcscale[s0] : 1.0f;
        const float2 u0 = *(const float2*)(X + (size_t)s0 * DF + lane * 2);
        ax = fmaf(u0.x, c0, ax); ay = fmaf(u0.y, c0, ay);
    }
    int deg = e1 - e0; if (deg < 1) deg = 1;
    float dsc = (MODE == 0) ? rsqrtf((float)deg) : (1.0f / (float)deg);
    float2 o; o.x = ax * dsc; o.y = ay * dsc;
    *(float2*)(out + (size_t)row * DF + lane * 2) = o;
}

// ---------------------------------------------------------------------------
// fp32 GEMM: Y[M,128] = sum_s A_s[M,128] @ W_s[128,128] + b0 + b1, opt ReLU.
// Block tile 64x128, 256 threads, thread = 8 rows x 4 cols. Inner loop k
// unrolled x4 with ds_read_b128 on both A and W -> VALU-bound.
// In-place (Y aliasing an A_s) is safe: each block reads only its own 64 rows
// and all A reads complete (barrier) before the store epilogue.
// ---------------------------------------------------------------------------
template<int NSRC, bool RELU>
__global__ __launch_bounds__(256, 3) void gemm_k(
    const float* __restrict__ A0, const float* __restrict__ A1, const float* __restrict__ A2,
    const float* __restrict__ W0, const float* __restrict__ W1, const float* __restrict__ W2,
    const float* __restrict__ b0, const float* __restrict__ b1,
    float* __restrict__ Y, int M)
{
    __shared__ float Ws[64 * 128];
    __shared__ float As[64 * 68];
    const int tid = threadIdx.x;
    const int r0 = blockIdx.x * 64;
    const int tr = tid >> 5;   // 0..7  -> rows tr*8..tr*8+7
    const int tc = tid & 31;   // 0..31 -> cols tc*4..tc*4+3

    float4 acc[8];
    #pragma unroll
    for (int i = 0; i < 8; ++i) acc[i] = make_float4(0.f, 0.f, 0.f, 0.f);

    const float* Aarr[3] = {A0, A1, A2};
    const float* Warr[3] = {W0, W1, W2};

    const int lr = tid >> 2;   // 0..63 (row within tile for loads)
    const int seg = tid & 3;   // 0..3
    int gr = r0 + lr; if (gr > M - 1) gr = M - 1;   // clamped load row

    #pragma unroll
    for (int s = 0; s < NSRC; ++s) {
        const float* A = Aarr[s];
        const float* W = Warr[s];
        for (int kc = 0; kc < 128; kc += 64) {
            __syncthreads();   // protect LDS reads of previous chunk
            const float4* Wg = (const float4*)(W + kc * 128);
            float4* Ws4 = (float4*)Ws;
            #pragma unroll
            for (int i = 0; i < 8; ++i) Ws4[tid + i * 256] = Wg[tid + i * 256];
            const float* Ar = A + (size_t)gr * DF + kc;
            #pragma unroll
            for (int i = 0; i < 4; ++i) {
                float4 v = *(const float4*)(Ar + (i * 4 + seg) * 4);
                *(float4*)(As + lr * 68 + (i * 4 + seg) * 4) = v;
            }
            __syncthreads();
            for (int k = 0; k < 64; k += 4) {
                float4 w0 = *(const float4*)(Ws + (k + 0) * 128 + tc * 4);
                float4 w1 = *(const float4*)(Ws + (k + 1) * 128 + tc * 4);
                float4 w2 = *(const float4*)(Ws + (k + 2) * 128 + tc * 4);
                float4 w3 = *(const float4*)(Ws + (k + 3) * 128 + tc * 4);
                #pragma unroll
                for (int i = 0; i < 8; ++i) {
                    float4 a = *(const float4*)(As + (tr * 8 + i) * 68 + k);
                    acc[i].x = fmaf(a.x, w0.x, acc[i].x);
                    acc[i].y = fmaf(a.x, w0.y, acc[i].y);
                    acc[i].z = fmaf(a.x, w0.z, acc[i].z);
                    acc[i].w = fmaf(a.x, w0.w, acc[i].w);
                    acc[i].x = fmaf(a.y, w1.x, acc[i].x);
                    acc[i].y = fmaf(a.y, w1.y, acc[i].y);
                    acc[i].z = fmaf(a.y, w1.z, acc[i].z);
                    acc[i].w = fmaf(a.y, w1.w, acc[i].w);
                    acc[i].x = fmaf(a.z, w2.x, acc[i].x);
                    acc[i].y = fmaf(a.z, w2.y, acc[i].y);
                    acc[i].z = fmaf(a.z, w2.z, acc[i].z);
                    acc[i].w = fmaf(a.z, w2.w, acc[i].w);
                    acc[i].x = fmaf(a.w, w3.x, acc[i].x);
                    acc[i].y = fmaf(a.w, w3.y, acc[i].y);
                    acc[i].z = fmaf(a.w, w3.z, acc[i].z);
                    acc[i].w = fmaf(a.w, w3.w, acc[i].w);
                }
            }
        }
    }

    float4 bias = make_float4(0.f, 0.f, 0.f, 0.f);
    if (b0) { bias.x  = b0[tc * 4]; bias.y  = b0[tc * 4 + 1]; bias.z  = b0[tc * 4 + 2]; bias.w  = b0[tc * 4 + 3]; }
    if (b1) { bias.x += b1[tc * 4]; bias.y += b1[tc * 4 + 1]; bias.z += b1[tc * 4 + 2]; bias.w += b1[tc * 4 + 3]; }

    #pragma unroll
    for (int i = 0; i < 8; ++i) {
        int r = r0 + tr * 8 + i;
        if (r < M) {
            float4 v;
            v.x = acc[i].x + bias.x; v.y = acc[i].y + bias.y;
            v.z = acc[i].z + bias.z; v.w = acc[i].w + bias.w;
            if (RELU) {
                v.x = fmaxf(v.x, 0.f); v.y = fmaxf(v.y, 0.f);
                v.z = fmaxf(v.z, 0.f); v.w = fmaxf(v.w, 0.f);
            }
            *(float4*)(Y + (size_t)r * DF + tc * 4) = v;
        }
    }
}

// ---------------------------------------------------------------------------
extern "C" void kernel_launch(void* const* d_in, const int* in_sizes, int n_in,
                              void* d_out, int out_size, void* d_ws, size_t ws_size,
                              hipStream_t stream)
{
    (void)in_sizes; (void)n_in; (void)out_size; (void)ws_size;
    const float* feat_C   = (const float*)d_in[0];
    const float* feat_N   = (const float*)d_in[1];
    const float* W1_cc    = (const float*)d_in[2];
    const float* b1_cc    = (const float*)d_in[3];
    const float* W1_cn    = (const float*)d_in[4];
    const float* b1_cn    = (const float*)d_in[5];
    const float* W1_self  = (const float*)d_in[6];
    const float* W1_neigh = (const float*)d_in[7];
    const float* b1_nn    = (const float*)d_in[8];
    const float* W2_cc    = (const float*)d_in[9];
    const float* b2_cc    = (const float*)d_in[10];
    const float* W2_cn    = (const float*)d_in[11];
    const float* b2_cn    = (const float*)d_in[12];
    const float* W2_self  = (const float*)d_in[13];
    const float* W2_neigh = (const float*)d_in[14];
    const float* b2_nn    = (const float*)d_in[15];
    const int* cc_src = (const int*)d_in[16];
    const int* cc_dst = (const int*)d_in[17];
    const int* cn_src = (const int*)d_in[18];
    const int* cn_dst = (const int*)d_in[19];
    const int* nn_src = (const int*)d_in[20];
    const int* nn_dst = (const int*)d_in[21];

    char* ws = (char*)d_ws;
    size_t off = 0;
    auto take = [&](size_t bytes) -> char* {
        char* p = ws + off;
        off = (off + bytes + 255) & ~(size_t)255;
        return p;
    };
    int*   rp3    = (int*)take((size_t)3 * (NCN + 1) * sizeof(int));
    int*   col3   = (int*)take((size_t)3 * NE * sizeof(int));
    float* snorm2 = (float*)take((size_t)2 * NCN * sizeof(float));
    int*   bc     = (int*)take((size_t)5 * BK * sizeof(int));
    // R (26.8MB) is dead after binB; overlap it with the agg buffers (51.2MB)
    char* bigRegion = take((size_t)2 * NCN * DF * sizeof(float));
    uint2* R    = (uint2*)bigRegion;
    float* aggA = (float*)bigRegion;
    float* aggB = (float*)(bigRegion + (size_t)NCN * DF * sizeof(float));

    float* oC = (float*)d_out;           // also hosts hC (layer-1)
    float* oN = oC + (size_t)NCN * DF;   // also hosts hN (layer-1)

    const int binABlocks = (NE + CHUNK - 1) / CHUNK;     // 123
    const int aggBlocks  = (NCN * 64 + 255) / 256;       // one wave per row
    const int gemmBlocks = (NCN + 63) / 64;

    // ---- CSR + norms via two-phase binning ----
    hipMemsetAsync(bc, 0, (size_t)5 * BK * sizeof(int), stream);
    binA_k<<<dim3(binABlocks, 5), 256, 0, stream>>>(cc_src, cc_dst, cn_src, cn_dst,
                                                    nn_src, nn_dst, R, bc);
    binB_k<<<dim3(NBUCK, 5), 256, 0, stream>>>(R, bc, rp3, col3, snorm2);

    // ---- layer 1 ----
    agg_pull_k<0><<<aggBlocks, 256, 0, stream>>>(feat_C, rp3 + 0 * (NCN + 1), col3 + 0 * NE,
                                                 snorm2 + 0 * NCN, aggA, NCN);
    gemm_k<1, true><<<gemmBlocks, 256, 0, stream>>>(aggA, nullptr, nullptr,
                                                    W1_cc, nullptr, nullptr,
                                                    b1_cc, nullptr, oC, NCN);
    agg_pull_k<0><<<aggBlocks, 256, 0, stream>>>(feat_C, rp3 + 1 * (NCN + 1), col3 + 1 * NE,
                                                 snorm2 + 1 * NCN, aggA, NCN);
    agg_pull_k<1><<<aggBlocks, 256, 0, stream>>>(feat_N, rp3 + 2 * (NCN + 1), col3 + 2 * NE,
                                                 nullptr, aggB, NCN);
    gemm_k<3, true><<<gemmBlocks, 256, 0, stream>>>(aggA, aggB, feat_N,
                                                    W1_cn, W1_neigh, W1_self,
                                                    b1_cn, b1_nn, oN, NCN);

    // ---- layer 2 ----
    agg_pull_k<0><<<aggBlocks, 256, 0, stream>>>(oC, rp3 + 0 * (NCN + 1), col3 + 0 * NE,
                                                 snorm2 + 0 * NCN, aggA, NCN);
    agg_pull_k<0><<<aggBlocks, 256, 0, stream>>>(oC, rp3 + 1 * (NCN + 1), col3 + 1 * NE,
                                                 snorm2 + 1 * NCN, aggB, NCN);
    gemm_k<1, false><<<gemmBlocks, 256, 0, stream>>>(aggA, nullptr, nullptr,
                                                     W2_cc, nullptr, nullptr,
                                                     b2_cc, nullptr, oC, NCN);
    agg_pull_k<1><<<aggBlocks, 256, 0, stream>>>(oN, rp3 + 2 * (NCN + 1), col3 + 2 * NE,
                                                 nullptr, aggA, NCN);
    gemm_k<3, false><<<gemmBlocks, 256, 0, stream>>>(aggB, aggA, oN,
                                                     W2_cn, W2_neigh, W2_self,
                                                     b2_cn, b2_nn, oN, NCN);
}

// Round 3
// 428.456 us; speedup vs baseline: 1.8665x; 1.2218x over previous
//
#include <hip/hip_runtime.h>

#define NCN 50000   // nodes per type (N_C == N_N)
#define NE  500000  // edges per type
#define DF  128     // feature dim

// Binning parameters
#define BSHIFT 9                 // 512 dst nodes per bucket
#define NBUCK 98                 // ceil(50000/512)
#define BK 128                   // padded bucket count
#define CAP 7168                 // records per bucket (expected ~5120, uniform)
#define CHUNK 4096               // edges per binA block

typedef __attribute__((ext_vector_type(8))) short mfrag;   // 8 bf16 (4 VGPRs)
typedef __attribute__((ext_vector_type(4))) float facc4;   // 4 fp32 acc

__device__ inline ushort f2bf(float x) {                   // fp32 -> bf16 RNE
    unsigned u = __float_as_uint(x);
    unsigned r = (u + 0x7FFFu + ((u >> 16) & 1u)) >> 16;
    return (ushort)r;
}
__device__ inline float bf2f(ushort h) { return __uint_as_float(((unsigned)h) << 16); }

// ---------------------------------------------------------------------------
// Phase A: block-local counting sort of CHUNK edges into NBUCK dst-buckets,
// flushed as contiguous runs (one global atomic per block x bucket).
// streams: 0=cc(dst,src) 1=cn(dst,src) 2=nn(dst,src) 3=cc_src 4=cn_src(count only)
// ---------------------------------------------------------------------------
__global__ __launch_bounds__(256) void binA_k(
    const int* __restrict__ cc_src, const int* __restrict__ cc_dst,
    const int* __restrict__ cn_src, const int* __restrict__ cn_dst,
    const int* __restrict__ nn_src, const int* __restrict__ nn_dst,
    uint2* __restrict__ R, int* __restrict__ bc)
{
    const int s = blockIdx.y;
    const int* key; const int* pay;
    switch (s) {
      case 0: key = cc_dst; pay = cc_src; break;
      case 1: key = cn_dst; pay = cn_src; break;
      case 2: key = nn_dst; pay = nn_src; break;
      case 3: key = cc_src; pay = nullptr; break;
      default: key = cn_src; pay = nullptr; break;
    }
    __shared__ uint2 rec[CHUNK];
    __shared__ int lhist[BK], lofs[BK], lcur[BK], gbase[BK];
    __shared__ int ls[256];
    const int tid = threadIdx.x;
    const int base = blockIdx.x * CHUNK;

    int k[16], p[16];
    #pragma unroll
    for (int j = 0; j < 16; ++j) {
        int e = base + j * 256 + tid;
        bool valid = (e < NE);
        k[j] = valid ? key[e] : -1;
        p[j] = (valid && pay) ? pay[e] : 0;
    }
    if (tid < BK) lhist[tid] = 0;
    __syncthreads();
    #pragma unroll
    for (int j = 0; j < 16; ++j)
        if (k[j] >= 0) atomicAdd(&lhist[k[j] >> BSHIFT], 1);
    __syncthreads();
    int v = (tid < BK) ? lhist[tid] : 0;
    ls[tid] = v;
    __syncthreads();
    #pragma unroll
    for (int off = 1; off < 128; off <<= 1) {
        int t = (tid >= off) ? ls[tid - off] : 0;
        __syncthreads();
        ls[tid] += t;
        __syncthreads();
    }
    if (tid < BK) { int e = ls[tid] - v; lofs[tid] = e; lcur[tid] = e; }
    __syncthreads();
    #pragma unroll
    for (int j = 0; j < 16; ++j) {
        if (k[j] >= 0) {
            int b = k[j] >> BSHIFT;
            int pos = atomicAdd(&lcur[b], 1);
            rec[pos] = make_uint2((unsigned)k[j], (unsigned)p[j]);
        }
    }
    __syncthreads();
    if (tid < BK) {
        int c = lcur[tid] - lofs[tid];
        gbase[tid] = (c > 0) ? atomicAdd(&bc[s * BK + tid], c) : 0;
    }
    __syncthreads();
    int total = ls[127];
    for (int i = tid; i < total; i += 256) {
        uint2 r = rec[i];
        int b = (int)(r.x >> BSHIFT);
        int gi = gbase[b] + (i - lofs[b]);
        R[((size_t)s * NBUCK + b) * CAP + gi] = r;
    }
}

// ---------------------------------------------------------------------------
// Phase B: one block per (bucket, stream).
// ---------------------------------------------------------------------------
__global__ __launch_bounds__(256) void binB_k(
    const uint2* __restrict__ R, const int* __restrict__ bc,
    int* __restrict__ rp3, int* __restrict__ col3, float* __restrict__ snorm2)
{
    const int b = blockIdx.x;
    const int s = blockIdx.y;
    const int tid = threadIdx.x;
    __shared__ int cnt[512];
    __shared__ int lofs[512];
    __shared__ int ls[256];
    __shared__ int sbase;

    const int nrec = bc[s * BK + b];
    const uint2* rec = R + ((size_t)s * NBUCK + b) * CAP;

    for (int i = tid; i < 512; i += 256) cnt[i] = 0;
    __syncthreads();
    for (int i = tid; i < nrec; i += 256)
        atomicAdd(&cnt[rec[i].x & 511], 1);
    __syncthreads();

    if (s >= 3) {
        float* sn = snorm2 + (size_t)(s - 3) * NCN;
        for (int j = tid; j < 512; j += 256) {
            int d = b * 512 + j;
            if (d < NCN) { int c = cnt[j]; if (c < 1) c = 1; sn[d] = rsqrtf((float)c); }
        }
        return;
    }

    {
        int v = (tid < b) ? bc[s * BK + tid] : 0;
        ls[tid] = v;
        __syncthreads();
        for (int off = 128; off > 0; off >>= 1) {
            if (tid < off) ls[tid] += ls[tid + off];
            __syncthreads();
        }
        if (tid == 0) sbase = ls[0];
        __syncthreads();
    }
    const int colBase = sbase;

    int v0 = cnt[2 * tid], v1 = cnt[2 * tid + 1];
    int pairSum = v0 + v1;
    ls[tid] = pairSum;
    __syncthreads();
    #pragma unroll
    for (int off = 1; off < 256; off <<= 1) {
        int t = (tid >= off) ? ls[tid - off] : 0;
        __syncthreads();
        ls[tid] += t;
        __syncthreads();
    }
    int excl = ls[tid] - pairSum;
    lofs[2 * tid] = excl;
    lofs[2 * tid + 1] = excl + v0;
    __syncthreads();
    const int total = ls[255];

    int* rp = rp3 + (size_t)s * (NCN + 1);
    for (int j = tid; j < 512; j += 256) {
        int d = b * 512 + j;
        if (d < NCN) rp[d] = colBase + lofs[j];
    }
    if (b == NBUCK - 1 && tid == 0) rp[NCN] = colBase + total;
    __syncthreads();

    int* col = col3 + (size_t)s * NE + colBase;
    for (int i = tid; i < nrec; i += 256) {
        uint2 r = rec[i];
        int pos = atomicAdd(&lofs[r.x & 511], 1);
        col[pos] = (int)r.y;
    }
}

// ---------------------------------------------------------------------------
// W preconvert: fp32 W[128][128] -> bf16 hi/lo "LDS image" per 64-k chunk,
// transposed (WT[n][k]) with the T2 XOR swizzle baked in so the GEMM does a
// plain linear copy to LDS and conflict-free ds_read_b128 fragment reads.
// Layout per matrix: [chunk(2)][hi 8192 | lo 8192] ushorts (64KB).
// img[c][n*64 + jj] = comp( W[c*64 + (jj ^ ((n&7)<<3))][n] )
// ---------------------------------------------------------------------------
__global__ __launch_bounds__(256) void wconv_k(
    const float* __restrict__ Wm0, const float* __restrict__ Wm1,
    const float* __restrict__ Wm2, const float* __restrict__ Wm3,
    const float* __restrict__ Wm4, const float* __restrict__ Wm5,
    const float* __restrict__ Wm6, const float* __restrict__ Wm7,
    ushort* __restrict__ out)
{
    const float* Ws[8] = {Wm0, Wm1, Wm2, Wm3, Wm4, Wm5, Wm6, Wm7};
    const float* W = Ws[blockIdx.x];
    ushort* o = out + (size_t)blockIdx.x * 32768;
    for (int i = threadIdx.x; i < 16384; i += 256) {
        int c = i >> 13;
        int r = i & 8191;
        int n = r >> 6;
        int jj = r & 63;
        int kk = c * 64 + (jj ^ ((n & 7) << 3));
        float wv = W[kk * 128 + n];
        ushort h = f2bf(wv);
        float lv = wv - bf2f(h);
        o[c * 16384 + r] = h;
        o[c * 16384 + 8192 + r] = f2bf(lv);
    }
}

// ---------------------------------------------------------------------------
// Pull aggregation: one wave per destination row, 2 floats/lane, unroll x4.
// ---------------------------------------------------------------------------
template<int MODE>
__global__ __launch_bounds__(256) void agg_pull_k(
    const float* __restrict__ X, const int* __restrict__ rowptr,
    const int* __restrict__ colidx, const float* __restrict__ srcscale,
    float* __restrict__ out, int n)
{
    int gid = blockIdx.x * 256 + threadIdx.x;
    int row = gid >> 6;
    int lane = threadIdx.x & 63;
    if (row >= n) return;
    int e0 = rowptr[row], e1 = rowptr[row + 1];
    float ax = 0.f, ay = 0.f;
    int e = e0;
    for (; e + 4 <= e1; e += 4) {
        int s0 = colidx[e], s1 = colidx[e + 1], s2 = colidx[e + 2], s3 = colidx[e + 3];
        float c0 = srcscale ? srcscale[s0] : 1.0f;
        float c1 = srcscale ? srcscale[s1] : 1.0f;
        float c2 = srcscale ? srcscale[s2] : 1.0f;
        float c3 = srcscale ? srcscale[s3] : 1.0f;
        const float2 u0 = *(const float2*)(X + (size_t)s0 * DF + lane * 2);
        const float2 u1 = *(const float2*)(X + (size_t)s1 * DF + lane * 2);
        const float2 u2 = *(const float2*)(X + (size_t)s2 * DF + lane * 2);
        const float2 u3 = *(const float2*)(X + (size_t)s3 * DF + lane * 2);
        ax = fmaf(u0.x, c0, ax); ay = fmaf(u0.y, c0, ay);
        ax = fmaf(u1.x, c1, ax); ay = fmaf(u1.y, c1, ay);
        ax = fmaf(u2.x, c2, ax); ay = fmaf(u2.y, c2, ay);
        ax = fmaf(u3.x, c3, ax); ay = fmaf(u3.y, c3, ay);
    }
    for (; e < e1; ++e) {
        int s0 = colidx[e];
        float c0 = srcscale ? srcscale[s0] : 1.0f;
        const float2 u0 = *(const float2*)(X + (size_t)s0 * DF + lane * 2);
        ax = fmaf(u0.x, c0, ax); ay = fmaf(u0.y, c0, ay);
    }
    int deg = e1 - e0; if (deg < 1) deg = 1;
    float dsc = (MODE == 0) ? rsqrtf((float)deg) : (1.0f / (float)deg);
    float2 o; o.x = ax * dsc; o.y = ay * dsc;
    *(float2*)(out + (size_t)row * DF + lane * 2) = o;
}

// ---------------------------------------------------------------------------
// Split-bf16 MFMA GEMM: Y[M,128] = sum_s A_s[M,128] @ W_s[128,128] (+b0+b1).
// fp32 = hi + lo (bf16 each); C += Ahi*Whi + Ahi*Wlo + Alo*Whi (rel err ~2^-18).
// Block: 256 thr (4 waves), tile 128x128, wave = 32 rows x 128 cols as
// 2x8 mfma_f32_16x16x32_bf16 fragments. K chunked by 64; A regs double-buffered.
// LDS 64KB: A hi/lo [128][64] + W hi/lo [128][64], XOR-swizzled (T2).
// In-place Y==A_s safe: block reads only its own 128 rows, stores at end.
// ---------------------------------------------------------------------------
template<int NSRC, bool RELU>
__global__ __launch_bounds__(256, 2) void mgemm_k(
    const float* __restrict__ A0, const float* __restrict__ A1, const float* __restrict__ A2,
    const ushort* __restrict__ Wi0, const ushort* __restrict__ Wi1, const ushort* __restrict__ Wi2,
    const float* __restrict__ b0, const float* __restrict__ b1,
    float* __restrict__ Y, int M)
{
    constexpr int NCH = 2 * NSRC;
    __shared__ ushort Asm[16384];   // hi [0,8192), lo [8192,16384)
    __shared__ ushort Wsm[16384];
    const int tid = threadIdx.x;
    const int l = tid & 63;
    const int wv = tid >> 6;
    const int r0 = blockIdx.x * 128;

    const float*  Aarr[3] = {A0, A1, A2};
    const ushort* Warr[3] = {Wi0, Wi1, Wi2};

    const int srow = tid >> 1;     // staging: 2 threads/row
    const int shalf = tid & 1;     // k-half (32 each)
    int grow = r0 + srow; if (grow > M - 1) grow = M - 1;

    facc4 acc[2][8];
    #pragma unroll
    for (int rt = 0; rt < 2; ++rt)
        #pragma unroll
        for (int ct = 0; ct < 8; ++ct)
            acc[rt][ct] = (facc4){0.f, 0.f, 0.f, 0.f};

    float4 ArA[8], ArB[8];
    uint4  Wr[8];

    auto loadA = [&](int c, float4* ar) {
        int s = c >> 1, k0 = (c & 1) * 64;
        const float4* ap = (const float4*)(Aarr[s] + (size_t)grow * DF + k0 + shalf * 32);
        #pragma unroll
        for (int i = 0; i < 8; ++i) ar[i] = ap[i];
    };
    auto loadW = [&](int c) {
        int s = c >> 1, cl = c & 1;
        const uint4* wp = (const uint4*)(Warr[s] + cl * 16384);
        #pragma unroll
        for (int i = 0; i < 8; ++i) Wr[i] = wp[i * 256 + tid];
    };
    auto writeW = [&]() {
        uint4* wd = (uint4*)Wsm;
        #pragma unroll
        for (int i = 0; i < 8; ++i) wd[i * 256 + tid] = Wr[i];
    };
    auto writeA = [&](const float4* ar) {
        #pragma unroll
        for (int g = 0; g < 4; ++g) {
            uint hp[4], lp[4];
            #pragma unroll
            for (int q = 0; q < 2; ++q) {
                float4 vq = ar[g * 2 + q];
                ushort h0 = f2bf(vq.x); ushort l0 = f2bf(vq.x - bf2f(h0));
                ushort h1 = f2bf(vq.y); ushort l1 = f2bf(vq.y - bf2f(h1));
                ushort h2 = f2bf(vq.z); ushort l2 = f2bf(vq.z - bf2f(h2));
                ushort h3 = f2bf(vq.w); ushort l3 = f2bf(vq.w - bf2f(h3));
                hp[q * 2]     = (uint)h0 | ((uint)h1 << 16);
                hp[q * 2 + 1] = (uint)h2 | ((uint)h3 << 16);
                lp[q * 2]     = (uint)l0 | ((uint)l1 << 16);
                lp[q * 2 + 1] = (uint)l2 | ((uint)l3 << 16);
            }
            int kbyte = shalf * 64 + g * 16;
            int idx = srow * 64 + ((kbyte ^ ((srow & 7) << 4)) >> 1);
            *(uint4*)(Asm + idx)        = make_uint4(hp[0], hp[1], hp[2], hp[3]);
            *(uint4*)(Asm + 8192 + idx) = make_uint4(lp[0], lp[1], lp[2], lp[3]);
        }
    };

    loadA(0, ArA);
    loadW(0);

    #pragma unroll
    for (int c = 0; c < NCH; ++c) {
        __syncthreads();
        if (c & 1) writeA(ArB); else writeA(ArA);
        writeW();
        if (c + 1 < NCH) {
            if (c & 1) loadA(c + 1, ArA); else loadA(c + 1, ArB);
            loadW(c + 1);
        }
        __syncthreads();
        #pragma unroll
        for (int ks = 0; ks < 2; ++ks) {
            const int kbyte = ks * 64 + (l >> 4) * 16;
            mfrag a_hi[2], a_lo[2];
            #pragma unroll
            for (int rt = 0; rt < 2; ++rt) {
                int row = wv * 32 + rt * 16 + (l & 15);
                int idx = row * 64 + ((kbyte ^ ((row & 7) << 4)) >> 1);
                a_hi[rt] = *(const mfrag*)(Asm + idx);
                a_lo[rt] = *(const mfrag*)(Asm + 8192 + idx);
            }
            #pragma unroll
            for (int ct = 0; ct < 8; ++ct) {
                int col = ct * 16 + (l & 15);
                int widx = col * 64 + ((kbyte ^ ((col & 7) << 4)) >> 1);
                mfrag w_hi = *(const mfrag*)(Wsm + widx);
                mfrag w_lo = *(const mfrag*)(Wsm + 8192 + widx);
                #pragma unroll
                for (int rt = 0; rt < 2; ++rt) {
                    acc[rt][ct] = __builtin_amdgcn_mfma_f32_16x16x32_bf16(a_hi[rt], w_hi, acc[rt][ct], 0, 0, 0);
                    acc[rt][ct] = __builtin_amdgcn_mfma_f32_16x16x32_bf16(a_hi[rt], w_lo, acc[rt][ct], 0, 0, 0);
                    acc[rt][ct] = __builtin_amdgcn_mfma_f32_16x16x32_bf16(a_lo[rt], w_hi, acc[rt][ct], 0, 0, 0);
                }
            }
        }
    }

    float bias[8];
    #pragma unroll
    for (int ct = 0; ct < 8; ++ct) {
        int col = ct * 16 + (l & 15);
        float bv = b0 ? b0[col] : 0.f;
        if (b1) bv += b1[col];
        bias[ct] = bv;
    }
    #pragma unroll
    for (int rt = 0; rt < 2; ++rt) {
        #pragma unroll
        for (int q = 0; q < 4; ++q) {
            int row = r0 + wv * 32 + rt * 16 + (l >> 4) * 4 + q;
            if (row < M) {
                #pragma unroll
                for (int ct = 0; ct < 8; ++ct) {
                    float v = acc[rt][ct][q] + bias[ct];
                    if (RELU) v = fmaxf(v, 0.f);
                    Y[(size_t)row * DF + ct * 16 + (l & 15)] = v;
                }
            }
        }
    }
}

// ---------------------------------------------------------------------------
extern "C" void kernel_launch(void* const* d_in, const int* in_sizes, int n_in,
                              void* d_out, int out_size, void* d_ws, size_t ws_size,
                              hipStream_t stream)
{
    (void)in_sizes; (void)n_in; (void)out_size; (void)ws_size;
    const float* feat_C   = (const float*)d_in[0];
    const float* feat_N   = (const float*)d_in[1];
    const float* W1_cc    = (const float*)d_in[2];
    const float* b1_cc    = (const float*)d_in[3];
    const float* W1_cn    = (const float*)d_in[4];
    const float* b1_cn    = (const float*)d_in[5];
    const float* W1_self  = (const float*)d_in[6];
    const float* W1_neigh = (const float*)d_in[7];
    const float* b1_nn    = (const float*)d_in[8];
    const float* W2_cc    = (const float*)d_in[9];
    const float* b2_cc    = (const float*)d_in[10];
    const float* W2_cn    = (const float*)d_in[11];
    const float* b2_cn    = (const float*)d_in[12];
    const float* W2_self  = (const float*)d_in[13];
    const float* W2_neigh = (const float*)d_in[14];
    const float* b2_nn    = (const float*)d_in[15];
    const int* cc_src = (const int*)d_in[16];
    const int* cc_dst = (const int*)d_in[17];
    const int* cn_src = (const int*)d_in[18];
    const int* cn_dst = (const int*)d_in[19];
    const int* nn_src = (const int*)d_in[20];
    const int* nn_dst = (const int*)d_in[21];

    char* ws = (char*)d_ws;
    size_t off = 0;
    auto take = [&](size_t bytes) -> char* {
        char* p = ws + off;
        off = (off + bytes + 255) & ~(size_t)255;
        return p;
    };
    int*    rp3    = (int*)take((size_t)3 * (NCN + 1) * sizeof(int));
    int*    col3   = (int*)take((size_t)3 * NE * sizeof(int));
    float*  snorm2 = (float*)take((size_t)2 * NCN * sizeof(float));
    int*    bc     = (int*)take((size_t)5 * BK * sizeof(int));
    ushort* Wimg   = (ushort*)take((size_t)8 * 32768 * sizeof(ushort));  // 512KB
    // R (26.8MB) is dead after binB; overlap it with the agg buffers (51.2MB)
    char* bigRegion = take((size_t)2 * NCN * DF * sizeof(float));
    uint2* R    = (uint2*)bigRegion;
    float* aggA = (float*)bigRegion;
    float* aggB = (float*)(bigRegion + (size_t)NCN * DF * sizeof(float));

    float* oC = (float*)d_out;           // also hosts hC (layer-1)
    float* oN = oC + (size_t)NCN * DF;   // also hosts hN (layer-1)

    const int binABlocks = (NE + CHUNK - 1) / CHUNK;
    const int aggBlocks  = (NCN * 64 + 255) / 256;
    const int gemmBlocks = (NCN + 127) / 128;

    // mats: 0:W1_cc 1:W1_cn 2:W1_neigh 3:W1_self 4:W2_cc 5:W2_cn 6:W2_neigh 7:W2_self
    const ushort* I0 = Wimg;
    auto img = [&](int m) { return I0 + (size_t)m * 32768; };

    // ---- CSR + norms + W preconvert ----
    hipMemsetAsync(bc, 0, (size_t)5 * BK * sizeof(int), stream);
    binA_k<<<dim3(binABlocks, 5), 256, 0, stream>>>(cc_src, cc_dst, cn_src, cn_dst,
                                                    nn_src, nn_dst, R, bc);
    binB_k<<<dim3(NBUCK, 5), 256, 0, stream>>>(R, bc, rp3, col3, snorm2);
    wconv_k<<<8, 256, 0, stream>>>(W1_cc, W1_cn, W1_neigh, W1_self,
                                   W2_cc, W2_cn, W2_neigh, W2_self, Wimg);

    // ---- layer 1 ----
    agg_pull_k<0><<<aggBlocks, 256, 0, stream>>>(feat_C, rp3 + 0 * (NCN + 1), col3 + 0 * NE,
                                                 snorm2 + 0 * NCN, aggA, NCN);
    mgemm_k<1, true><<<gemmBlocks, 256, 0, stream>>>(aggA, nullptr, nullptr,
                                                     img(0), nullptr, nullptr,
                                                     b1_cc, nullptr, oC, NCN);
    agg_pull_k<0><<<aggBlocks, 256, 0, stream>>>(feat_C, rp3 + 1 * (NCN + 1), col3 + 1 * NE,
                                                 snorm2 + 1 * NCN, aggA, NCN);
    agg_pull_k<1><<<aggBlocks, 256, 0, stream>>>(feat_N, rp3 + 2 * (NCN + 1), col3 + 2 * NE,
                                                 nullptr, aggB, NCN);
    mgemm_k<3, true><<<gemmBlocks, 256, 0, stream>>>(aggA, aggB, feat_N,
                                                     img(1), img(2), img(3),
                                                     b1_cn, b1_nn, oN, NCN);

    // ---- layer 2 ----
    agg_pull_k<0><<<aggBlocks, 256, 0, stream>>>(oC, rp3 + 0 * (NCN + 1), col3 + 0 * NE,
                                                 snorm2 + 0 * NCN, aggA, NCN);
    agg_pull_k<0><<<aggBlocks, 256, 0, stream>>>(oC, rp3 + 1 * (NCN + 1), col3 + 1 * NE,
                                                 snorm2 + 1 * NCN, aggB, NCN);
    mgemm_k<1, false><<<gemmBlocks, 256, 0, stream>>>(aggA, nullptr, nullptr,
                                                      img(4), nullptr, nullptr,
                                                      b2_cc, nullptr, oC, NCN);
    agg_pull_k<1><<<aggBlocks, 256, 0, stream>>>(oN, rp3 + 2 * (NCN + 1), col3 + 2 * NE,
                                                 nullptr, aggA, NCN);
    mgemm_k<3, false><<<gemmBlocks, 256, 0, stream>>>(aggB, aggA, oN,
                                                      img(5), img(6), img(7),
                                                      b2_cn, b2_nn, oN, NCN);
}

// Round 4
// 416.363 us; speedup vs baseline: 1.9207x; 1.0290x over previous
//
#include <hip/hip_runtime.h>

#define NCN 50000   // nodes per type (N_C == N_N)
#define NE  500000  // edges per type
#define DF  128     // feature dim

// Binning parameters
#define BSHIFT 9                 // 512 dst nodes per bucket
#define NBUCK 98                 // ceil(50000/512)
#define BK 128                   // padded bucket count
#define CAP 7168                 // records per bucket (expected ~5120, uniform)
#define CHUNK 4096               // edges per binA block

typedef __attribute__((ext_vector_type(8))) short mfrag;   // 8 bf16 (4 VGPRs)
typedef __attribute__((ext_vector_type(4))) float facc4;   // 4 fp32 acc

__device__ inline ushort f2bf(float x) {                   // fp32 -> bf16 RNE
    unsigned u = __float_as_uint(x);
    unsigned r = (u + 0x7FFFu + ((u >> 16) & 1u)) >> 16;
    return (ushort)r;
}
__device__ inline float bf2f(ushort h) { return __uint_as_float(((unsigned)h) << 16); }

// split-bf16 store: H table at T, L table at T + NCN*DF (ushort each)
__device__ inline void store_split(ushort* __restrict__ T, int row, int lane,
                                   float vx, float vy) {
    ushort hx = f2bf(vx); ushort lx = f2bf(vx - bf2f(hx));
    ushort hy = f2bf(vy); ushort ly = f2bf(vy - bf2f(hy));
    uint hp = (uint)hx | ((uint)hy << 16);
    uint lp = (uint)lx | ((uint)ly << 16);
    *(uint*)(T + (size_t)row * DF + lane * 2) = hp;
    *(uint*)(T + (size_t)NCN * DF + (size_t)row * DF + lane * 2) = lp;
}

// ---------------------------------------------------------------------------
// Phase A: block-local counting sort of CHUNK edges into NBUCK dst-buckets,
// flushed as contiguous runs (one global atomic per block x bucket).
// streams: 0=cc(dst,src) 1=cn(dst,src) 2=nn(dst,src) 3=cc_src 4=cn_src(count only)
// ---------------------------------------------------------------------------
__global__ __launch_bounds__(256) void binA_k(
    const int* __restrict__ cc_src, const int* __restrict__ cc_dst,
    const int* __restrict__ cn_src, const int* __restrict__ cn_dst,
    const int* __restrict__ nn_src, const int* __restrict__ nn_dst,
    uint2* __restrict__ R, int* __restrict__ bc)
{
    const int s = blockIdx.y;
    const int* key; const int* pay;
    switch (s) {
      case 0: key = cc_dst; pay = cc_src; break;
      case 1: key = cn_dst; pay = cn_src; break;
      case 2: key = nn_dst; pay = nn_src; break;
      case 3: key = cc_src; pay = nullptr; break;
      default: key = cn_src; pay = nullptr; break;
    }
    __shared__ uint2 rec[CHUNK];
    __shared__ int lhist[BK], lofs[BK], lcur[BK], gbase[BK];
    __shared__ int ls[256];
    const int tid = threadIdx.x;
    const int base = blockIdx.x * CHUNK;

    int k[16], p[16];
    #pragma unroll
    for (int j = 0; j < 16; ++j) {
        int e = base + j * 256 + tid;
        bool valid = (e < NE);
        k[j] = valid ? key[e] : -1;
        p[j] = (valid && pay) ? pay[e] : 0;
    }
    if (tid < BK) lhist[tid] = 0;
    __syncthreads();
    #pragma unroll
    for (int j = 0; j < 16; ++j)
        if (k[j] >= 0) atomicAdd(&lhist[k[j] >> BSHIFT], 1);
    __syncthreads();
    int v = (tid < BK) ? lhist[tid] : 0;
    ls[tid] = v;
    __syncthreads();
    #pragma unroll
    for (int off = 1; off < 128; off <<= 1) {
        int t = (tid >= off) ? ls[tid - off] : 0;
        __syncthreads();
        ls[tid] += t;
        __syncthreads();
    }
    if (tid < BK) { int e = ls[tid] - v; lofs[tid] = e; lcur[tid] = e; }
    __syncthreads();
    #pragma unroll
    for (int j = 0; j < 16; ++j) {
        if (k[j] >= 0) {
            int b = k[j] >> BSHIFT;
            int pos = atomicAdd(&lcur[b], 1);
            rec[pos] = make_uint2((unsigned)k[j], (unsigned)p[j]);
        }
    }
    __syncthreads();
    if (tid < BK) {
        int c = lcur[tid] - lofs[tid];
        gbase[tid] = (c > 0) ? atomicAdd(&bc[s * BK + tid], c) : 0;
    }
    __syncthreads();
    int total = ls[127];
    for (int i = tid; i < total; i += 256) {
        uint2 r = rec[i];
        int b = (int)(r.x >> BSHIFT);
        int gi = gbase[b] + (i - lofs[b]);
        R[((size_t)s * NBUCK + b) * CAP + gi] = r;
    }
}

// ---------------------------------------------------------------------------
// Phase B: one block per (bucket, stream).
// ---------------------------------------------------------------------------
__global__ __launch_bounds__(256) void binB_k(
    const uint2* __restrict__ R, const int* __restrict__ bc,
    int* __restrict__ rp3, int* __restrict__ col3, float* __restrict__ snorm2)
{
    const int b = blockIdx.x;
    const int s = blockIdx.y;
    const int tid = threadIdx.x;
    __shared__ int cnt[512];
    __shared__ int lofs[512];
    __shared__ int ls[256];
    __shared__ int sbase;

    const int nrec = bc[s * BK + b];
    const uint2* rec = R + ((size_t)s * NBUCK + b) * CAP;

    for (int i = tid; i < 512; i += 256) cnt[i] = 0;
    __syncthreads();
    for (int i = tid; i < nrec; i += 256)
        atomicAdd(&cnt[rec[i].x & 511], 1);
    __syncthreads();

    if (s >= 3) {
        float* sn = snorm2 + (size_t)(s - 3) * NCN;
        for (int j = tid; j < 512; j += 256) {
            int d = b * 512 + j;
            if (d < NCN) { int c = cnt[j]; if (c < 1) c = 1; sn[d] = rsqrtf((float)c); }
        }
        return;
    }

    {
        int v = (tid < b) ? bc[s * BK + tid] : 0;
        ls[tid] = v;
        __syncthreads();
        for (int off = 128; off > 0; off >>= 1) {
            if (tid < off) ls[tid] += ls[tid + off];
            __syncthreads();
        }
        if (tid == 0) sbase = ls[0];
        __syncthreads();
    }
    const int colBase = sbase;

    int v0 = cnt[2 * tid], v1 = cnt[2 * tid + 1];
    int pairSum = v0 + v1;
    ls[tid] = pairSum;
    __syncthreads();
    #pragma unroll
    for (int off = 1; off < 256; off <<= 1) {
        int t = (tid >= off) ? ls[tid - off] : 0;
        __syncthreads();
        ls[tid] += t;
        __syncthreads();
    }
    int excl = ls[tid] - pairSum;
    lofs[2 * tid] = excl;
    lofs[2 * tid + 1] = excl + v0;
    __syncthreads();
    const int total = ls[255];

    int* rp = rp3 + (size_t)s * (NCN + 1);
    for (int j = tid; j < 512; j += 256) {
        int d = b * 512 + j;
        if (d < NCN) rp[d] = colBase + lofs[j];
    }
    if (b == NBUCK - 1 && tid == 0) rp[NCN] = colBase + total;
    __syncthreads();

    int* col = col3 + (size_t)s * NE + colBase;
    for (int i = tid; i < nrec; i += 256) {
        uint2 r = rec[i];
        int pos = atomicAdd(&lofs[r.x & 511], 1);
        col[pos] = (int)r.y;
    }
}

// ---------------------------------------------------------------------------
// W preconvert: fp32 W[128][128] -> bf16 hi/lo image per 64-k chunk,
// transposed with the XOR swizzle baked in (read-side XOR cancels it).
// Layout per matrix: [chunk(2)][hi 8192 | lo 8192] ushorts (64KB).
// ---------------------------------------------------------------------------
__global__ __launch_bounds__(256) void wconv_k(
    const float* __restrict__ Wm0, const float* __restrict__ Wm1,
    const float* __restrict__ Wm2, const float* __restrict__ Wm3,
    const float* __restrict__ Wm4, const float* __restrict__ Wm5,
    const float* __restrict__ Wm6, const float* __restrict__ Wm7,
    ushort* __restrict__ out)
{
    const float* Ws[8] = {Wm0, Wm1, Wm2, Wm3, Wm4, Wm5, Wm6, Wm7};
    const float* W = Ws[blockIdx.x];
    ushort* o = out + (size_t)blockIdx.x * 32768;
    for (int i = threadIdx.x; i < 16384; i += 256) {
        int c = i >> 13;
        int r = i & 8191;
        int n = r >> 6;
        int jj = r & 63;
        int kk = c * 64 + (jj ^ ((n & 7) << 3));
        float wv = W[kk * 128 + n];
        ushort h = f2bf(wv);
        float lv = wv - bf2f(h);
        o[c * 16384 + r] = h;
        o[c * 16384 + 8192 + r] = f2bf(lv);
    }
}

// ---------------------------------------------------------------------------
// Pull aggregation, GraphConv norm (MODE 0), TWO independent streams per
// dispatch (blockIdx.y), split-bf16 output.
// ---------------------------------------------------------------------------
__global__ __launch_bounds__(256) void agg2_k(
    const float* __restrict__ X,
    const int* __restrict__ rpA, const int* __restrict__ colA,
    const float* __restrict__ scA, ushort* __restrict__ outA,
    const int* __restrict__ rpB, const int* __restrict__ colB,
    const float* __restrict__ scB, ushort* __restrict__ outB)
{
    const int* rp; const int* col; const float* sc; ushort* out;
    if (blockIdx.y == 0) { rp = rpA; col = colA; sc = scA; out = outA; }
    else                 { rp = rpB; col = colB; sc = scB; out = outB; }
    int gid = blockIdx.x * 256 + threadIdx.x;
    int row = gid >> 6;
    int lane = threadIdx.x & 63;
    if (row >= NCN) return;
    int e0 = rp[row], e1 = rp[row + 1];
    float ax = 0.f, ay = 0.f;
    int e = e0;
    for (; e + 4 <= e1; e += 4) {
        int s0 = col[e], s1 = col[e + 1], s2 = col[e + 2], s3 = col[e + 3];
        float c0 = sc[s0], c1 = sc[s1], c2 = sc[s2], c3 = sc[s3];
        const float2 u0 = *(const float2*)(X + (size_t)s0 * DF + lane * 2);
        const float2 u1 = *(const float2*)(X + (size_t)s1 * DF + lane * 2);
        const float2 u2 = *(const float2*)(X + (size_t)s2 * DF + lane * 2);
        const float2 u3 = *(const float2*)(X + (size_t)s3 * DF + lane * 2);
        ax = fmaf(u0.x, c0, ax); ay = fmaf(u0.y, c0, ay);
        ax = fmaf(u1.x, c1, ax); ay = fmaf(u1.y, c1, ay);
        ax = fmaf(u2.x, c2, ax); ay = fmaf(u2.y, c2, ay);
        ax = fmaf(u3.x, c3, ax); ay = fmaf(u3.y, c3, ay);
    }
    for (; e < e1; ++e) {
        int s0 = col[e];
        float c0 = sc[s0];
        const float2 u0 = *(const float2*)(X + (size_t)s0 * DF + lane * 2);
        ax = fmaf(u0.x, c0, ax); ay = fmaf(u0.y, c0, ay);
    }
    int deg = e1 - e0; if (deg < 1) deg = 1;
    float dsc = rsqrtf((float)deg);
    store_split(out, row, lane, ax * dsc, ay * dsc);
}

// SAGE mean aggregation (single stream), split-bf16 output.
__global__ __launch_bounds__(256) void agg1_k(
    const float* __restrict__ X, const int* __restrict__ rp,
    const int* __restrict__ col, ushort* __restrict__ out)
{
    int gid = blockIdx.x * 256 + threadIdx.x;
    int row = gid >> 6;
    int lane = threadIdx.x & 63;
    if (row >= NCN) return;
    int e0 = rp[row], e1 = rp[row + 1];
    float ax = 0.f, ay = 0.f;
    int e = e0;
    for (; e + 4 <= e1; e += 4) {
        int s0 = col[e], s1 = col[e + 1], s2 = col[e + 2], s3 = col[e + 3];
        const float2 u0 = *(const float2*)(X + (size_t)s0 * DF + lane * 2);
        const float2 u1 = *(const float2*)(X + (size_t)s1 * DF + lane * 2);
        const float2 u2 = *(const float2*)(X + (size_t)s2 * DF + lane * 2);
        const float2 u3 = *(const float2*)(X + (size_t)s3 * DF + lane * 2);
        ax += u0.x + u1.x + u2.x + u3.x;
        ay += u0.y + u1.y + u2.y + u3.y;
    }
    for (; e < e1; ++e) {
        int s0 = col[e];
        const float2 u0 = *(const float2*)(X + (size_t)s0 * DF + lane * 2);
        ax += u0.x; ay += u0.y;
    }
    int deg = e1 - e0; if (deg < 1) deg = 1;
    float dsc = 1.0f / (float)deg;
    store_split(out, row, lane, ax * dsc, ay * dsc);
}

// ---------------------------------------------------------------------------
// Split-bf16 MFMA GEMM, A-fragments loaded DIRECTLY from global (no A-LDS).
// Y[M,128] = sum_s A_s[M,128] @ W_s[128,128] (+b0+b1), opt ReLU.
// Sources: split tables (H at p, L at p + NCN*DF) except source F32S (fp32,
// converted in-registers). Block: 256 thr (4 waves), tile 128x128; wave =
// 32 rows, 2x8 mfma_f32_16x16x32_bf16 frags; 3 products hi*hi+hi*lo+lo*hi.
// LDS 32KB: W hi/lo for one 64-k chunk (reg-staged, swizzled image).
// In-place Y==A_s safe: block reads only its own 128 rows; stores at end.
// ---------------------------------------------------------------------------
template<int NSRC, bool RELU, int F32S>
__global__ __launch_bounds__(256, 3) void mgemm_k(
    const void* __restrict__ A0, const void* __restrict__ A1, const void* __restrict__ A2,
    const ushort* __restrict__ Wi0, const ushort* __restrict__ Wi1, const ushort* __restrict__ Wi2,
    const float* __restrict__ b0, const float* __restrict__ b1,
    float* __restrict__ Y, int M)
{
    constexpr int NCH = 2 * NSRC;
    __shared__ ushort Wsm[16384];   // hi [0,8192) | lo [8192,16384) ushorts
    const int tid = threadIdx.x;
    const int l = tid & 63;
    const int wv = tid >> 6;
    const int r0 = blockIdx.x * 128;

    const void*   Aarr[3] = {A0, A1, A2};
    const ushort* Warr[3] = {Wi0, Wi1, Wi2};

    int arow[2];
    #pragma unroll
    for (int rt = 0; rt < 2; ++rt) {
        int r = r0 + wv * 32 + rt * 16 + (l & 15);
        arow[rt] = (r < M) ? r : (M - 1);
    }
    const int kgrp = (l >> 4) * 8;   // element offset within a 32-k step

    facc4 acc[2][8];
    #pragma unroll
    for (int rt = 0; rt < 2; ++rt)
        #pragma unroll
        for (int ct = 0; ct < 8; ++ct)
            acc[rt][ct] = (facc4){0.f, 0.f, 0.f, 0.f};

    uint4 Wr[8];
    auto loadWr = [&](int c) {
        int s = c >> 1, half = c & 1;
        const uint4* wp = (const uint4*)(Warr[s] + half * 16384);
        #pragma unroll
        for (int i = 0; i < 8; ++i) Wr[i] = wp[i * 256 + tid];
    };

    mfrag ah[2][2], al[2][2];   // [ks][rt]
    auto loadA = [&](int c) {
        int s = c >> 1;
        int k0 = (c & 1) * 64;
        if (s == F32S) {
            const float* F = (const float*)Aarr[s];
            #pragma unroll
            for (int ks = 0; ks < 2; ++ks)
                #pragma unroll
                for (int rt = 0; rt < 2; ++rt) {
                    const float* p = F + (size_t)arow[rt] * DF + k0 + ks * 32 + kgrp;
                    float4 v0 = *(const float4*)p;
                    float4 v1 = *(const float4*)(p + 4);
                    union { mfrag m; ushort u[8]; } H, L;
                    float vv0[4] = {v0.x, v0.y, v0.z, v0.w};
                    float vv1[4] = {v1.x, v1.y, v1.z, v1.w};
                    #pragma unroll
                    for (int j = 0; j < 4; ++j) {
                        ushort h = f2bf(vv0[j]);
                        H.u[j] = h; L.u[j] = f2bf(vv0[j] - bf2f(h));
                    }
                    #pragma unroll
                    for (int j = 0; j < 4; ++j) {
                        ushort h = f2bf(vv1[j]);
                        H.u[4 + j] = h; L.u[4 + j] = f2bf(vv1[j] - bf2f(h));
                    }
                    ah[ks][rt] = H.m; al[ks][rt] = L.m;
                }
        } else {
            const ushort* T = (const ushort*)Aarr[s];
            #pragma unroll
            for (int ks = 0; ks < 2; ++ks)
                #pragma unroll
                for (int rt = 0; rt < 2; ++rt) {
                    size_t o = (size_t)arow[rt] * DF + k0 + ks * 32 + kgrp;
                    ah[ks][rt] = *(const mfrag*)(T + o);
                    al[ks][rt] = *(const mfrag*)(T + (size_t)NCN * DF + o);
                }
        }
    };

    loadWr(0);
    #pragma unroll
    for (int c = 0; c < NCH; ++c) {
        __syncthreads();   // all waves done reading Wsm(prev)
        {
            uint4* wd = (uint4*)Wsm;
            #pragma unroll
            for (int i = 0; i < 8; ++i) wd[i * 256 + tid] = Wr[i];
        }
        loadA(c);
        if (c + 1 < NCH) loadWr(c + 1);
        __syncthreads();   // Wsm(c) visible
        #pragma unroll
        for (int ks = 0; ks < 2; ++ks) {
            const int kbyte = ks * 64 + (l >> 4) * 16;
            #pragma unroll
            for (int ct = 0; ct < 8; ++ct) {
                int colc = ct * 16 + (l & 15);
                int widx = colc * 64 + ((kbyte ^ ((colc & 7) << 4)) >> 1);
                mfrag w_hi = *(const mfrag*)(Wsm + widx);
                mfrag w_lo = *(const mfrag*)(Wsm + 8192 + widx);
                #pragma unroll
                for (int rt = 0; rt < 2; ++rt) {
                    acc[rt][ct] = __builtin_amdgcn_mfma_f32_16x16x32_bf16(ah[ks][rt], w_hi, acc[rt][ct], 0, 0, 0);
                    acc[rt][ct] = __builtin_amdgcn_mfma_f32_16x16x32_bf16(ah[ks][rt], w_lo, acc[rt][ct], 0, 0, 0);
                    acc[rt][ct] = __builtin_amdgcn_mfma_f32_16x16x32_bf16(al[ks][rt], w_hi, acc[rt][ct], 0, 0, 0);
                }
            }
        }
    }

    float bias[8];
    #pragma unroll
    for (int ct = 0; ct < 8; ++ct) {
        int colc = ct * 16 + (l & 15);
        float bv = b0 ? b0[colc] : 0.f;
        if (b1) bv += b1[colc];
        bias[ct] = bv;
    }
    #pragma unroll
    for (int rt = 0; rt < 2; ++rt) {
        #pragma unroll
        for (int q = 0; q < 4; ++q) {
            int row = r0 + wv * 32 + rt * 16 + (l >> 4) * 4 + q;
            if (row < M) {
                #pragma unroll
                for (int ct = 0; ct < 8; ++ct) {
                    float v = acc[rt][ct][q] + bias[ct];
                    if (RELU) v = fmaxf(v, 0.f);
                    Y[(size_t)row * DF + ct * 16 + (l & 15)] = v;
                }
            }
        }
    }
}

// ---------------------------------------------------------------------------
extern "C" void kernel_launch(void* const* d_in, const int* in_sizes, int n_in,
                              void* d_out, int out_size, void* d_ws, size_t ws_size,
                              hipStream_t stream)
{
    (void)in_sizes; (void)n_in; (void)out_size; (void)ws_size;
    const float* feat_C   = (const float*)d_in[0];
    const float* feat_N   = (const float*)d_in[1];
    const float* W1_cc    = (const float*)d_in[2];
    const float* b1_cc    = (const float*)d_in[3];
    const float* W1_cn    = (const float*)d_in[4];
    const float* b1_cn    = (const float*)d_in[5];
    const float* W1_self  = (const float*)d_in[6];
    const float* W1_neigh = (const float*)d_in[7];
    const float* b1_nn    = (const float*)d_in[8];
    const float* W2_cc    = (const float*)d_in[9];
    const float* b2_cc    = (const float*)d_in[10];
    const float* W2_cn    = (const float*)d_in[11];
    const float* b2_cn    = (const float*)d_in[12];
    const float* W2_self  = (const float*)d_in[13];
    const float* W2_neigh = (const float*)d_in[14];
    const float* b2_nn    = (const float*)d_in[15];
    const int* cc_src = (const int*)d_in[16];
    const int* cc_dst = (const int*)d_in[17];
    const int* cn_src = (const int*)d_in[18];
    const int* cn_dst = (const int*)d_in[19];
    const int* nn_src = (const int*)d_in[20];
    const int* nn_dst = (const int*)d_in[21];

    char* ws = (char*)d_ws;
    size_t off = 0;
    auto take = [&](size_t bytes) -> char* {
        char* p = ws + off;
        off = (off + bytes + 255) & ~(size_t)255;
        return p;
    };
    int*    rp3    = (int*)take((size_t)3 * (NCN + 1) * sizeof(int));
    int*    col3   = (int*)take((size_t)3 * NE * sizeof(int));
    float*  snorm2 = (float*)take((size_t)2 * NCN * sizeof(float));
    int*    bc     = (int*)take((size_t)5 * BK * sizeof(int));
    ushort* Wimg   = (ushort*)take((size_t)8 * 32768 * sizeof(ushort));  // 512KB
    // R (26.8MB) dead after binB; overlap with the two split tables (51.2MB)
    char* bigRegion = take((size_t)2 * 2 * NCN * DF * sizeof(ushort));
    uint2*  R  = (uint2*)bigRegion;
    ushort* P0 = (ushort*)bigRegion;                                  // 25.6MB
    ushort* P1 = (ushort*)(bigRegion + (size_t)2 * NCN * DF * sizeof(ushort));

    float* oC = (float*)d_out;           // also hosts hC (layer-1)
    float* oN = oC + (size_t)NCN * DF;   // also hosts hN (layer-1)

    const int binABlocks = (NE + CHUNK - 1) / CHUNK;
    const int aggBlocks  = (NCN * 64 + 255) / 256;
    const int gemmBlocks = (NCN + 127) / 128;

    // mats: 0:W1_cc 1:W1_cn 2:W1_neigh 3:W1_self 4:W2_cc 5:W2_cn 6:W2_neigh 7:W2_self
    auto img = [&](int m) { return (const ushort*)(Wimg + (size_t)m * 32768); };
    const int* rpCC = rp3 + 0 * (NCN + 1);
    const int* rpCN = rp3 + 1 * (NCN + 1);
    const int* rpNN = rp3 + 2 * (NCN + 1);
    const int* colCC = col3 + 0 * NE;
    const int* colCN = col3 + 1 * NE;
    const int* colNN = col3 + 2 * NE;
    const float* snCC = snorm2 + 0 * NCN;
    const float* snCN = snorm2 + 1 * NCN;

    // ---- CSR + norms + W preconvert ----
    hipMemsetAsync(bc, 0, (size_t)5 * BK * sizeof(int), stream);
    binA_k<<<dim3(binABlocks, 5), 256, 0, stream>>>(cc_src, cc_dst, cn_src, cn_dst,
                                                    nn_src, nn_dst, R, bc);
    binB_k<<<dim3(NBUCK, 5), 256, 0, stream>>>(R, bc, rp3, col3, snorm2);
    wconv_k<<<8, 256, 0, stream>>>(W1_cc, W1_cn, W1_neigh, W1_self,
                                   W2_cc, W2_cn, W2_neigh, W2_self, Wimg);

    // ---- layer 1 ----
    // cc->P0, cn->P1 (both gather feat_C)
    agg2_k<<<dim3(aggBlocks, 2), 256, 0, stream>>>(feat_C,
                                                   rpCC, colCC, snCC, P0,
                                                   rpCN, colCN, snCN, P1);
    mgemm_k<1, true, -1><<<gemmBlocks, 256, 0, stream>>>(P0, nullptr, nullptr,
                                                         img(0), nullptr, nullptr,
                                                         b1_cc, nullptr, oC, NCN);
    agg1_k<<<aggBlocks, 256, 0, stream>>>(feat_N, rpNN, colNN, P0);   // nn -> P0
    mgemm_k<3, true, 2><<<gemmBlocks, 256, 0, stream>>>(P1, P0, feat_N,
                                                        img(1), img(2), img(3),
                                                        b1_cn, b1_nn, oN, NCN);

    // ---- layer 2 ----
    // cn->P1, cc->P0 (both gather hC = oC, before oC is overwritten)
    agg2_k<<<dim3(aggBlocks, 2), 256, 0, stream>>>(oC,
                                                   rpCN, colCN, snCN, P1,
                                                   rpCC, colCC, snCC, P0);
    mgemm_k<1, false, -1><<<gemmBlocks, 256, 0, stream>>>(P0, nullptr, nullptr,
                                                          img(4), nullptr, nullptr,
                                                          b2_cc, nullptr, oC, NCN);
    agg1_k<<<aggBlocks, 256, 0, stream>>>(oN, rpNN, colNN, P0);       // nn -> P0
    // in-place: reads hN (= oN) as fp32 A2 (own block rows), writes oN
    mgemm_k<3, false, 2><<<gemmBlocks, 256, 0, stream>>>(P1, P0, oN,
                                                         img(5), img(6), img(7),
                                                         b2_cn, b2_nn, oN, NCN);
}